// Round 3
// baseline (65827.142 us; speedup 1.0000x reference)
//
#include <hip/hip_runtime.h>
#include <hip/hip_fp16.h>
#include <cstdint>

// ============================================================================
// BiLSTM(2-layer, H=512) + FC + CRF NLL  — fp32 with ws-adaptive fp16 xg plan
//
//   1. embed gather                         (x0 = emb[X], aliased into x1 region)
//   2. input projection GEMM per direction  (xg = x @ w_ih^T + b_ih + b_hh)
//   3. persistent LSTM scan (256 blocks, plain launch; capacity argument:
//      2 blocks/CU fit -> all 256 co-resident on an exclusive 256-CU chip;
//      hand-rolled hierarchical grid barrier with per-thread release fences)
//   4. layer-1: GEMM K=1024 + scan, output aliases x1
//   5. FC (K=1024 -> 9) writes logits into d_out+1
//   6. CRF (one wave per batch)   7. loss finalize
//
// Memory plans (selected on ws_size; constant across calls -> capture-safe):
//   Plan A (ws >= 322 MiB): xg buffers f32  (64 + 128 + 128 MiB + eps)
//   Plan B (else):          xg buffers fp16 (64 +  64 +  64 MiB + eps)
// ============================================================================

#define BB 32
#define LL 512
#define EE 256
#define HH 512
#define NC 9
#define G4 2048          // 4*H
#define ML (BB*LL)       // 16384

// ---------------------------------------------------------------------------
// 1. Embedding gather
// ---------------------------------------------------------------------------
__global__ __launch_bounds__(256) void embed_kernel(const int* __restrict__ X,
                                                    const float* __restrict__ emb,
                                                    float* __restrict__ x0) {
  int gid = blockIdx.x * 256 + threadIdx.x;   // one float4 per thread
  int tok = gid >> 6;                          // 64 float4 per token (E=256)
  int e4  = gid & 63;
  int row = X[tok];
  const float4* src = (const float4*)(emb + (size_t)row * EE);
  float4* dst = (float4*)(x0 + (size_t)tok * EE);
  dst[e4] = src[e4];
}

// ---------------------------------------------------------------------------
// 2. GEMM: C[M][N] = A[M][K] @ W[N][K]^T + b1[n] + b2[n]   (OT = float | __half)
//    BM=BN=128, BK=16, 256 threads, 8x8 microtile.
// ---------------------------------------------------------------------------
__device__ inline void store8(float* p, const float* v) {
  *(float4*)p       = *(const float4*)v;
  *(float4*)(p + 4) = *(const float4*)(v + 4);
}
__device__ inline void store8(__half* p, const float* v) {
  __half h[8];
#pragma unroll
  for (int j = 0; j < 8; ++j) h[j] = __float2half(v[j]);
  *(float4*)p = *(const float4*)h;   // 16 B
}

template <typename OT>
__global__ __launch_bounds__(256) void gemm_bias_kernel(
    const float* __restrict__ A, const float* __restrict__ W,
    const float* __restrict__ b1, const float* __restrict__ b2,
    OT* __restrict__ C, int M, int N, int K) {
  __shared__ float As[16][132];
  __shared__ float Ws[16][132];
  const int tid = threadIdx.x;
  const int bn = blockIdx.x, bm = blockIdx.y;
  const int tx = tid & 15, ty = tid >> 4;

  float acc[8][8];
#pragma unroll
  for (int i = 0; i < 8; ++i)
#pragma unroll
    for (int j = 0; j < 8; ++j) acc[i][j] = 0.f;

  const int m_l = tid >> 1;            // 0..127
  const int k_l = (tid & 1) * 8;       // 0 or 8
  const float* Arow = A + (size_t)(bm * 128 + m_l) * K + k_l;
  const float* Wrow = W + (size_t)(bn * 128 + m_l) * K + k_l;

  for (int k0 = 0; k0 < K; k0 += 16) {
    float4 a0 = *(const float4*)(Arow + k0);
    float4 a1 = *(const float4*)(Arow + k0 + 4);
    float4 w0 = *(const float4*)(Wrow + k0);
    float4 w1 = *(const float4*)(Wrow + k0 + 4);
    __syncthreads();
    As[k_l + 0][m_l] = a0.x; As[k_l + 1][m_l] = a0.y;
    As[k_l + 2][m_l] = a0.z; As[k_l + 3][m_l] = a0.w;
    As[k_l + 4][m_l] = a1.x; As[k_l + 5][m_l] = a1.y;
    As[k_l + 6][m_l] = a1.z; As[k_l + 7][m_l] = a1.w;
    Ws[k_l + 0][m_l] = w0.x; Ws[k_l + 1][m_l] = w0.y;
    Ws[k_l + 2][m_l] = w0.z; Ws[k_l + 3][m_l] = w0.w;
    Ws[k_l + 4][m_l] = w1.x; Ws[k_l + 5][m_l] = w1.y;
    Ws[k_l + 6][m_l] = w1.z; Ws[k_l + 7][m_l] = w1.w;
    __syncthreads();
#pragma unroll
    for (int kk = 0; kk < 16; ++kk) {
      float4 aA = *(const float4*)&As[kk][ty * 8];
      float4 aB = *(const float4*)&As[kk][ty * 8 + 4];
      float4 wA = *(const float4*)&Ws[kk][tx * 8];
      float4 wB = *(const float4*)&Ws[kk][tx * 8 + 4];
      float av[8] = {aA.x, aA.y, aA.z, aA.w, aB.x, aB.y, aB.z, aB.w};
      float wv[8] = {wA.x, wA.y, wA.z, wA.w, wB.x, wB.y, wB.z, wB.w};
#pragma unroll
      for (int i = 0; i < 8; ++i)
#pragma unroll
        for (int j = 0; j < 8; ++j) acc[i][j] += av[i] * wv[j];
    }
  }
  const int gm = bm * 128 + ty * 8;
  const int gn = bn * 128 + tx * 8;
  float bias[8];
#pragma unroll
  for (int j = 0; j < 8; ++j) bias[j] = b1[gn + j] + b2[gn + j];
#pragma unroll
  for (int i = 0; i < 8; ++i) {
    float o8[8];
#pragma unroll
    for (int j = 0; j < 8; ++j) o8[j] = acc[i][j] + bias[j];
    store8(C + (size_t)(gm + i) * N + gn, o8);
  }
}

// ---------------------------------------------------------------------------
// 3. Persistent LSTM scan (both directions in one launch).
//    grid = 256 blocks (dir = blockIdx>>7, hidden-slice = blockIdx&127, J=4),
//    512 threads. W_hh slice in registers (4 rows x 32 k / thread).
//    h double-buffered in global [2 buf][2 dir][512 j][32 b]; LDS-staged.
//    Grid barrier: 8 arrival counters + 1 release counter; every writer
//    thread fences its own stores before arrival (XCD L2 non-coherence).
// ---------------------------------------------------------------------------
template <typename XgT>
__global__ __launch_bounds__(512) void lstm_scan_kernel(
    const XgT* __restrict__ xg_f, const XgT* __restrict__ xg_r,
    const float* __restrict__ whh_f, const float* __restrict__ whh_r,
    float* __restrict__ xout,      // [ML][1024], cols dir*512 + j
    float* __restrict__ hbuf,      // [2 buf][2 dir][512 j][32 b]
    int* __restrict__ bar) {
  __shared__ float smem[16384];    // 64 KB: h_s [512 j][32 b]  (aliased: red+gates)
  float* red     = smem;           // [16 ks][32 mt][20]
  float* gates_s = smem + 10240;   // [32 b][20]

  const int tid = threadIdx.x;
  const int dir = blockIdx.x >> 7;
  const int blk = blockIdx.x & 127;
  const int j0  = blk * 4;
  const XgT*   xg  = dir ? xg_r  : xg_f;
  const float* whh = dir ? whh_r : whh_f;

  // dot-phase role
  const int ks   = tid >> 5;            // 0..15 (k chunk)
  const int mt   = tid & 31;            // microtile id
  const int b0   = (mt & 7) * 4;        // batch base
  const int gate = mt >> 3;             // 0..3 (i,f,g,o)

  // W_hh preload: rows gate*512 + j0 + ri, k = ks*32 + kk
  float wreg[4][32];
#pragma unroll
  for (int ri = 0; ri < 4; ++ri) {
    const float* wrow = whh + (size_t)(gate * 512 + j0 + ri) * 512 + ks * 32;
#pragma unroll
    for (int kq = 0; kq < 8; ++kq) {
      float4 v = *(const float4*)(wrow + kq * 4);
      wreg[ri][kq * 4 + 0] = v.x; wreg[ri][kq * 4 + 1] = v.y;
      wreg[ri][kq * 4 + 2] = v.z; wreg[ri][kq * 4 + 3] = v.w;
    }
  }

  // reducer role: output (b_red, r_red)
  const int a_r   = tid >> 5;                         // 0..15
  const int b_red = (mt & 7) * 4 + (a_r & 3);
  const int r_red = (mt >> 3) * 4 + (a_r >> 2);       // = gate*4 + jj
  const int n_red = (r_red >> 2) * 512 + j0 + (r_red & 3);  // xg column

  // update role (threads 0..31): c state in registers
  float c_state[4] = {0.f, 0.f, 0.f, 0.f};

#pragma unroll 1
  for (int t = 0; t < 512; ++t) {
    const int t_act = dir ? (511 - t) : t;
    const int rbuf  = t & 1;

    // ---- stage h_{t-1} into LDS ([j][b] layout, linear copy) ----
    float4* h4 = (float4*)smem;
    if (t == 0) {
      float4 z; z.x = z.y = z.z = z.w = 0.f;
#pragma unroll
      for (int i = 0; i < 8; ++i) h4[i * 512 + tid] = z;
    } else {
      const float4* src = (const float4*)(hbuf + (size_t)(rbuf * 2 + dir) * 16384);
#pragma unroll
      for (int i = 0; i < 8; ++i) h4[i * 512 + tid] = src[i * 512 + tid];
    }
    // prefetch xg for reducer role (used after dot loop)
    float xgv = (float)xg[((size_t)b_red * 512 + t_act) * 2048 + n_red];
    __syncthreads();

    // ---- dot: acc[ri][bi] += W_hh[row][k] * h[k][b0+bi], k in this chunk ----
    float accv[4][4];
#pragma unroll
    for (int ri = 0; ri < 4; ++ri)
#pragma unroll
      for (int bi = 0; bi < 4; ++bi) accv[ri][bi] = 0.f;
    const float* hk = smem + ks * 1024;   // (k = ks*32+kk) -> smem[k*32 + b]
#pragma unroll
    for (int kk = 0; kk < 32; ++kk) {
      float4 hv = *(const float4*)(hk + kk * 32 + b0);
#pragma unroll
      for (int ri = 0; ri < 4; ++ri) {
        float w = wreg[ri][kk];
        accv[ri][0] += w * hv.x; accv[ri][1] += w * hv.y;
        accv[ri][2] += w * hv.z; accv[ri][3] += w * hv.w;
      }
    }
    __syncthreads();   // h_s consumed; red may overwrite

    // ---- write partials to LDS ----
    float* myred = red + (size_t)(ks * 32 + mt) * 20;
#pragma unroll
    for (int ri = 0; ri < 4; ++ri) {
      float4 v;
      v.x = accv[ri][0]; v.y = accv[ri][1]; v.z = accv[ri][2]; v.w = accv[ri][3];
      *(float4*)(myred + ri * 4) = v;   // a = ri*4 + bi
    }
    __syncthreads();

    // ---- reduce across 16 k-chunks, add xg (biases folded into xg) ----
    float g = xgv;
#pragma unroll
    for (int k2 = 0; k2 < 16; ++k2) g += red[(size_t)(k2 * 32 + mt) * 20 + a_r];
    gates_s[b_red * 20 + r_red] = g;
    __syncthreads();

    // ---- cell update (threads 0..31, one batch each, 4 hidden units) ----
    if (tid < 32) {
      const int b = tid;
      const float* gv = gates_s + b * 20;
      float hout[4];
#pragma unroll
      for (int jj = 0; jj < 4; ++jj) {
        float gi = gv[jj], gf = gv[4 + jj], gg = gv[8 + jj], go = gv[12 + jj];
        float iv = 1.f / (1.f + expf(-gi));
        float fv = 1.f / (1.f + expf(-gf));
        float gz = tanhf(gg);
        float ov = 1.f / (1.f + expf(-go));
        float c  = fv * c_state[jj] + iv * gz;
        c_state[jj] = c;
        hout[jj] = ov * tanhf(c);
      }
      float4 ho4; ho4.x = hout[0]; ho4.y = hout[1]; ho4.z = hout[2]; ho4.w = hout[3];
      *(float4*)(xout + ((size_t)b * 512 + t_act) * 1024 + dir * 512 + j0) = ho4;
      float* hb = hbuf + (size_t)(((t + 1) & 1) * 2 + dir) * 16384;
#pragma unroll
      for (int jj = 0; jj < 4; ++jj) hb[(j0 + jj) * 32 + b] = hout[jj];
      __threadfence();   // each writer publishes its own stores (device scope)
    }

    // ---- grid barrier (skip after final step) ----
    if (t < 511) {
      __syncthreads();
      if (tid == 0) {
        const int grp = blockIdx.x & 7;
        int old = __hip_atomic_fetch_add(&bar[grp * 64], 1, __ATOMIC_ACQ_REL,
                                         __HIP_MEMORY_SCOPE_AGENT);
        if (old == (t + 1) * 32 - 1) {
          __hip_atomic_fetch_add(&bar[512], 1, __ATOMIC_ACQ_REL,
                                 __HIP_MEMORY_SCOPE_AGENT);
        }
        while (__hip_atomic_load(&bar[512], __ATOMIC_ACQUIRE,
                                 __HIP_MEMORY_SCOPE_AGENT) < (t + 1) * 8) {
          __builtin_amdgcn_s_sleep(1);
        }
      }
      __syncthreads();
      __threadfence();   // reader side: invalidate before re-reading hbuf
    }
  }
}

// ---------------------------------------------------------------------------
// 5. FC: logits[tok][c] = x2[tok] . fc_w[c] + fc_b[c]   (one wave per token)
// ---------------------------------------------------------------------------
__global__ __launch_bounds__(256) void fc_kernel(const float* __restrict__ x2,
                                                 const float* __restrict__ fc_w,
                                                 const float* __restrict__ fc_b,
                                                 float* __restrict__ logits) {
  const int wave = threadIdx.x >> 6, lane = threadIdx.x & 63;
  const int tok = blockIdx.x * 4 + wave;
  const float* xr = x2 + (size_t)tok * 1024;
  float4 xv[4];
#pragma unroll
  for (int i = 0; i < 4; ++i) xv[i] = *(const float4*)(xr + lane * 16 + i * 4);
  float out[NC];
#pragma unroll
  for (int c = 0; c < NC; ++c) {
    float acc = 0.f;
#pragma unroll
    for (int i = 0; i < 4; ++i) {
      float4 wv = *(const float4*)(fc_w + (size_t)c * 1024 + lane * 16 + i * 4);
      acc += xv[i].x * wv.x + xv[i].y * wv.y + xv[i].z * wv.z + xv[i].w * wv.w;
    }
#pragma unroll
    for (int off = 32; off >= 1; off >>= 1) acc += __shfl_down(acc, off, 64);
    out[c] = acc;
  }
  if (lane == 0) {
#pragma unroll
    for (int c = 0; c < NC; ++c) logits[(size_t)tok * NC + c] = out[c] + fc_b[c];
  }
}

// ---------------------------------------------------------------------------
// 6. CRF log-likelihood per batch (one wave per batch)
// ---------------------------------------------------------------------------
__global__ __launch_bounds__(64) void crf_kernel(const float* __restrict__ logits,
                                                 const int* __restrict__ labels,
                                                 const float* __restrict__ startv,
                                                 const float* __restrict__ endv,
                                                 const float* __restrict__ trans,
                                                 float* __restrict__ llh) {
  const int b = blockIdx.x, lane = threadIdx.x;
  const int* lab = labels + b * LL;
  const float* lg = logits + (size_t)b * LL * NC;

  // numerator (all 64 lanes strided over t)
  float part = 0.f; int cnt = 0;
  for (int t = lane; t < LL; t += 64) {
    int l = lab[t];
    int m = (l > -1);
    cnt += m;
    if (t >= 1) {
      int lp = lab[t - 1];
      int tp = (lp > -1) ? lp : 0;
      int tc = m ? l : 0;
      float v = trans[tp * NC + tc] + lg[(size_t)t * NC + tc];
      part += m ? v : 0.f;
    }
  }
#pragma unroll
  for (int off = 32; off >= 1; off >>= 1) {
    part += __shfl_down(part, off, 64);
    cnt  += __shfl_down(cnt, off, 64);
  }
  float num = 0.f;
  if (lane == 0) {
    int t0 = (lab[0] > -1) ? lab[0] : 0;
    num = startv[t0] + lg[t0] + part;
    int lastidx = cnt - 1;
    int lt = lab[lastidx]; lt = (lt > -1) ? lt : 0;
    num += endv[lt];
  }

  // forward algorithm (lanes 0..8 hold alpha_j)
  const int j = (lane < NC) ? lane : 0;
  float tr[NC];
#pragma unroll
  for (int i = 0; i < NC; ++i) tr[i] = trans[i * NC + j];
  float alpha = startv[j] + lg[j];
  for (int t = 1; t < LL; ++t) {
    float e = lg[(size_t)t * NC + j];
    float v[NC];
    float m = -3.4e38f;
#pragma unroll
    for (int i = 0; i < NC; ++i) {
      float ai = __shfl(alpha, i, 64);
      v[i] = ai + tr[i];
      m = fmaxf(m, v[i]);
    }
    float s = 0.f;
#pragma unroll
    for (int i = 0; i < NC; ++i) s += expf(v[i] - m);
    float cand = m + logf(s) + e;
    alpha = (lab[t] > -1) ? cand : alpha;
  }
  float av = alpha + endv[j];
  float vals[NC];
#pragma unroll
  for (int i = 0; i < NC; ++i) vals[i] = __shfl(av, i, 64);
  if (lane == 0) {
    float m2 = vals[0];
#pragma unroll
    for (int i = 1; i < NC; ++i) m2 = fmaxf(m2, vals[i]);
    float s2 = 0.f;
#pragma unroll
    for (int i = 0; i < NC; ++i) s2 += expf(vals[i] - m2);
    llh[b] = num - (m2 + logf(s2));
  }
}

// ---------------------------------------------------------------------------
// 7. finalize: loss = -sum(llh)
// ---------------------------------------------------------------------------
__global__ __launch_bounds__(64) void finalize_kernel(const float* __restrict__ llh,
                                                      float* __restrict__ out) {
  const int lane = threadIdx.x;
  float v = (lane < BB) ? llh[lane] : 0.f;
#pragma unroll
  for (int off = 32; off >= 1; off >>= 1) v += __shfl_down(v, off, 64);
  if (lane == 0) out[0] = -v;
}

// ---------------------------------------------------------------------------
template <typename XgT>
static void run_pipeline(const float* emb, const int* X,
                         const float* wi0, const float* wh0, const float* bi0, const float* bh0,
                         const float* wi0r, const float* wh0r, const float* bi0r, const float* bh0r,
                         const float* wi1, const float* wh1, const float* bi1, const float* bh1,
                         const float* wi1r, const float* wh1r, const float* bi1r, const float* bh1r,
                         float* x1, float* x0, XgT* xgf, XgT* xgr,
                         float* hbuf, int* bar0, int* bar1, hipStream_t stream) {
  embed_kernel<<<ML * EE / (256 * 4), 256, 0, stream>>>(X, emb, x0);
  dim3 gg(G4 / 128, ML / 128);   // (16, 128)
  gemm_bias_kernel<XgT><<<gg, 256, 0, stream>>>(x0, wi0,  bi0,  bh0,  xgf, ML, G4, EE);
  gemm_bias_kernel<XgT><<<gg, 256, 0, stream>>>(x0, wi0r, bi0r, bh0r, xgr, ML, G4, EE);
  lstm_scan_kernel<XgT><<<256, 512, 0, stream>>>(xgf, xgr, wh0, wh0r, x1, hbuf, bar0);
  gemm_bias_kernel<XgT><<<gg, 256, 0, stream>>>(x1, wi1,  bi1,  bh1,  xgf, ML, G4, 1024);
  gemm_bias_kernel<XgT><<<gg, 256, 0, stream>>>(x1, wi1r, bi1r, bh1r, xgr, ML, G4, 1024);
  lstm_scan_kernel<XgT><<<256, 512, 0, stream>>>(xgf, xgr, wh1, wh1r, x1 /*x2*/, hbuf, bar1);
}

extern "C" void kernel_launch(void* const* d_in, const int* in_sizes, int n_in,
                              void* d_out, int out_size, void* d_ws, size_t ws_size,
                              hipStream_t stream) {
  const int*   X       = (const int*)d_in[0];
  const int*   labels  = (const int*)d_in[1];
  const float* emb     = (const float*)d_in[2];
  const float* w_ih_l0  = (const float*)d_in[3];
  const float* w_hh_l0  = (const float*)d_in[4];
  const float* b_ih_l0  = (const float*)d_in[5];
  const float* b_hh_l0  = (const float*)d_in[6];
  const float* w_ih_l0r = (const float*)d_in[7];
  const float* w_hh_l0r = (const float*)d_in[8];
  const float* b_ih_l0r = (const float*)d_in[9];
  const float* b_hh_l0r = (const float*)d_in[10];
  const float* w_ih_l1  = (const float*)d_in[11];
  const float* w_hh_l1  = (const float*)d_in[12];
  const float* b_ih_l1  = (const float*)d_in[13];
  const float* b_hh_l1  = (const float*)d_in[14];
  const float* w_ih_l1r = (const float*)d_in[15];
  const float* w_hh_l1r = (const float*)d_in[16];
  const float* b_ih_l1r = (const float*)d_in[17];
  const float* b_hh_l1r = (const float*)d_in[18];
  const float* fc_w     = (const float*)d_in[19];
  const float* fc_b     = (const float*)d_in[20];
  const float* crf_start = (const float*)d_in[21];
  const float* crf_end   = (const float*)d_in[22];
  const float* crf_trans = (const float*)d_in[23];

  float* out = (float*)d_out;          // out[0]=loss, out+1 = logits [ML][9]
  const size_t MiB = 1024 * 1024;
  char* ws = (char*)d_ws;

  // x1 region: 64 MiB f32; x0 (16 MiB) aliased at its start (dead after L0 GEMMs)
  float* x1 = (float*)ws;
  float* x0 = x1;
  char* p = ws + 64 * MiB;

  const bool planA = ws_size >= 322 * MiB;
  const size_t xgBytes = planA ? 128 * MiB : 64 * MiB;
  void* xgf = (void*)p; p += xgBytes;
  void* xgr = (void*)p; p += xgBytes;
  float* hbuf = (float*)p; p += 256 * 1024;          // [2][2][512][32] f32
  int* bar0 = (int*)p; p += 4096;
  int* bar1 = (int*)p; p += 4096;
  float* llh = (float*)p; p += 4096;

  // zero the barrier counters (ws is re-poisoned to 0xAA before every launch)
  hipMemsetAsync(bar0, 0, 2 * 4096, stream);

  if (planA) {
    run_pipeline<float>(emb, X, w_ih_l0, w_hh_l0, b_ih_l0, b_hh_l0,
                        w_ih_l0r, w_hh_l0r, b_ih_l0r, b_hh_l0r,
                        w_ih_l1, w_hh_l1, b_ih_l1, b_hh_l1,
                        w_ih_l1r, w_hh_l1r, b_ih_l1r, b_hh_l1r,
                        x1, x0, (float*)xgf, (float*)xgr, hbuf, bar0, bar1, stream);
  } else {
    run_pipeline<__half>(emb, X, w_ih_l0, w_hh_l0, b_ih_l0, b_hh_l0,
                         w_ih_l0r, w_hh_l0r, b_ih_l0r, b_hh_l0r,
                         w_ih_l1, w_hh_l1, b_ih_l1, b_hh_l1,
                         w_ih_l1r, w_hh_l1r, b_ih_l1r, b_hh_l1r,
                         x1, x0, (__half*)xgf, (__half*)xgr, hbuf, bar0, bar1, stream);
  }

  fc_kernel<<<ML / 4, 256, 0, stream>>>(x1, fc_w, fc_b, out + 1);
  crf_kernel<<<BB, 64, 0, stream>>>(out + 1, labels, crf_start, crf_end, crf_trans, llh);
  finalize_kernel<<<1, 64, 0, stream>>>(llh, out);
}

// Round 4
// 34009.265 us; speedup vs baseline: 1.9356x; 1.9356x over previous
//
#include <hip/hip_runtime.h>
#include <hip/hip_fp16.h>
#include <cstdint>

// ============================================================================
// BiLSTM(2-layer, H=512) + FC + CRF NLL  — fp32 with ws-adaptive fp16 xg plan
//
//   1. embed gather                         (x0 = emb[X], aliased into x1 region)
//   2. input projection GEMM per direction  (xg = x @ w_ih^T + b_ih + b_hh)
//   3. persistent LSTM scan (256 blocks; hand-rolled PER-DIRECTION hierarchical
//      grid barrier: relaxed polls + ONE acquire fence per step — the round-3
//      version polled with ACQUIRE => buffer_inv per iteration => 60ms scans)
//   4. layer-1: GEMM K=1024 + scan, output aliases x1
//   5. FC (K=1024 -> 9) writes logits into d_out+1
//   6. CRF (one wave per batch)   7. loss finalize
//
// Memory plans (selected on ws_size; constant across calls -> capture-safe):
//   Plan A (ws >= 322 MiB): xg buffers f32
//   Plan B (else):          xg buffers fp16 (validated round 3: absmax 0.0156 PASS)
// ============================================================================

#define BB 32
#define LL 512
#define EE 256
#define HH 512
#define NC 9
#define G4 2048          // 4*H
#define ML (BB*LL)       // 16384

// ---------------------------------------------------------------------------
// 1. Embedding gather
// ---------------------------------------------------------------------------
__global__ __launch_bounds__(256) void embed_kernel(const int* __restrict__ X,
                                                    const float* __restrict__ emb,
                                                    float* __restrict__ x0) {
  int gid = blockIdx.x * 256 + threadIdx.x;   // one float4 per thread
  int tok = gid >> 6;                          // 64 float4 per token (E=256)
  int e4  = gid & 63;
  int row = X[tok];
  const float4* src = (const float4*)(emb + (size_t)row * EE);
  float4* dst = (float4*)(x0 + (size_t)tok * EE);
  dst[e4] = src[e4];
}

// ---------------------------------------------------------------------------
// 2. GEMM: C[M][N] = A[M][K] @ W[N][K]^T + b1[n] + b2[n]   (OT = float | __half)
//    BM=BN=128, BK=16, 256 threads, 8x8 microtile.
// ---------------------------------------------------------------------------
__device__ inline void store8(float* p, const float* v) {
  *(float4*)p       = *(const float4*)v;
  *(float4*)(p + 4) = *(const float4*)(v + 4);
}
__device__ inline void store8(__half* p, const float* v) {
  __half h[8];
#pragma unroll
  for (int j = 0; j < 8; ++j) h[j] = __float2half(v[j]);
  *(float4*)p = *(const float4*)h;   // 16 B
}

template <typename OT>
__global__ __launch_bounds__(256) void gemm_bias_kernel(
    const float* __restrict__ A, const float* __restrict__ W,
    const float* __restrict__ b1, const float* __restrict__ b2,
    OT* __restrict__ C, int M, int N, int K) {
  __shared__ float As[16][132];
  __shared__ float Ws[16][132];
  const int tid = threadIdx.x;
  const int bn = blockIdx.x, bm = blockIdx.y;
  const int tx = tid & 15, ty = tid >> 4;

  float acc[8][8];
#pragma unroll
  for (int i = 0; i < 8; ++i)
#pragma unroll
    for (int j = 0; j < 8; ++j) acc[i][j] = 0.f;

  const int m_l = tid >> 1;            // 0..127
  const int k_l = (tid & 1) * 8;       // 0 or 8
  const float* Arow = A + (size_t)(bm * 128 + m_l) * K + k_l;
  const float* Wrow = W + (size_t)(bn * 128 + m_l) * K + k_l;

  for (int k0 = 0; k0 < K; k0 += 16) {
    float4 a0 = *(const float4*)(Arow + k0);
    float4 a1 = *(const float4*)(Arow + k0 + 4);
    float4 w0 = *(const float4*)(Wrow + k0);
    float4 w1 = *(const float4*)(Wrow + k0 + 4);
    __syncthreads();
    As[k_l + 0][m_l] = a0.x; As[k_l + 1][m_l] = a0.y;
    As[k_l + 2][m_l] = a0.z; As[k_l + 3][m_l] = a0.w;
    As[k_l + 4][m_l] = a1.x; As[k_l + 5][m_l] = a1.y;
    As[k_l + 6][m_l] = a1.z; As[k_l + 7][m_l] = a1.w;
    Ws[k_l + 0][m_l] = w0.x; Ws[k_l + 1][m_l] = w0.y;
    Ws[k_l + 2][m_l] = w0.z; Ws[k_l + 3][m_l] = w0.w;
    Ws[k_l + 4][m_l] = w1.x; Ws[k_l + 5][m_l] = w1.y;
    Ws[k_l + 6][m_l] = w1.z; Ws[k_l + 7][m_l] = w1.w;
    __syncthreads();
#pragma unroll
    for (int kk = 0; kk < 16; ++kk) {
      float4 aA = *(const float4*)&As[kk][ty * 8];
      float4 aB = *(const float4*)&As[kk][ty * 8 + 4];
      float4 wA = *(const float4*)&Ws[kk][tx * 8];
      float4 wB = *(const float4*)&Ws[kk][tx * 8 + 4];
      float av[8] = {aA.x, aA.y, aA.z, aA.w, aB.x, aB.y, aB.z, aB.w};
      float wv[8] = {wA.x, wA.y, wA.z, wA.w, wB.x, wB.y, wB.z, wB.w};
#pragma unroll
      for (int i = 0; i < 8; ++i)
#pragma unroll
        for (int j = 0; j < 8; ++j) acc[i][j] += av[i] * wv[j];
    }
  }
  const int gm = bm * 128 + ty * 8;
  const int gn = bn * 128 + tx * 8;
  float bias[8];
#pragma unroll
  for (int j = 0; j < 8; ++j) bias[j] = b1[gn + j] + b2[gn + j];
#pragma unroll
  for (int i = 0; i < 8; ++i) {
    float o8[8];
#pragma unroll
    for (int j = 0; j < 8; ++j) o8[j] = acc[i][j] + bias[j];
    store8(C + (size_t)(gm + i) * N + gn, o8);
  }
}

// ---------------------------------------------------------------------------
// 3. Persistent LSTM scan (both directions in one launch).
//    grid = 256 blocks (dir = blockIdx>>7, hidden-slice = blockIdx&127, J=4),
//    512 threads. W_hh slice in registers (4 rows x 32 k / thread).
//    h double-buffered in global [2 buf][2 dir][512 j][32 b]; LDS-staged.
//    Grid barrier PER DIRECTION (128 blocks): 8 arrival counters + 1 release
//    counter. RELAXED polls (no buffer_inv per iteration!), one release fence
//    by the writer wave before arrival, one acquire fence per block per step.
// ---------------------------------------------------------------------------
template <typename XgT>
__global__ __launch_bounds__(512) void lstm_scan_kernel(
    const XgT* __restrict__ xg_f, const XgT* __restrict__ xg_r,
    const float* __restrict__ whh_f, const float* __restrict__ whh_r,
    float* __restrict__ xout,      // [ML][1024], cols dir*512 + j
    float* __restrict__ hbuf,      // [2 buf][2 dir][512 j][32 b]
    int* __restrict__ bar) {       // per dir: 1024 ints (8 grp lines + release)
  __shared__ float smem[16384];    // 64 KB: h_s [512 j][32 b]  (aliased: red+gates)
  float* red     = smem;           // [16 ks][32 mt][20]
  float* gates_s = smem + 10240;   // [32 b][20]

  const int tid = threadIdx.x;
  const int dir = blockIdx.x >> 7;
  const int blk = blockIdx.x & 127;
  const int j0  = blk * 4;
  const XgT*   xg  = dir ? xg_r  : xg_f;
  const float* whh = dir ? whh_r : whh_f;
  int* mybar = bar + dir * 1024;   // independent barrier per direction

  // dot-phase role
  const int ks   = tid >> 5;            // 0..15 (k chunk)
  const int mt   = tid & 31;            // microtile id
  const int b0   = (mt & 7) * 4;        // batch base
  const int gate = mt >> 3;             // 0..3 (i,f,g,o)

  // W_hh preload: rows gate*512 + j0 + ri, k = ks*32 + kk
  float wreg[4][32];
#pragma unroll
  for (int ri = 0; ri < 4; ++ri) {
    const float* wrow = whh + (size_t)(gate * 512 + j0 + ri) * 512 + ks * 32;
#pragma unroll
    for (int kq = 0; kq < 8; ++kq) {
      float4 v = *(const float4*)(wrow + kq * 4);
      wreg[ri][kq * 4 + 0] = v.x; wreg[ri][kq * 4 + 1] = v.y;
      wreg[ri][kq * 4 + 2] = v.z; wreg[ri][kq * 4 + 3] = v.w;
    }
  }

  // reducer role: output (b_red, r_red)
  const int a_r   = tid >> 5;                         // 0..15
  const int b_red = (mt & 7) * 4 + (a_r & 3);
  const int r_red = (mt >> 3) * 4 + (a_r >> 2);       // = gate*4 + jj
  const int n_red = (r_red >> 2) * 512 + j0 + (r_red & 3);  // xg column

  // update role (threads 0..31): c state in registers
  float c_state[4] = {0.f, 0.f, 0.f, 0.f};

#pragma unroll 1
  for (int t = 0; t < 512; ++t) {
    const int t_act = dir ? (511 - t) : t;
    const int rbuf  = t & 1;

    // ---- stage h_{t-1} into LDS ([j][b] layout, linear copy) ----
    float4* h4 = (float4*)smem;
    if (t == 0) {
      float4 z; z.x = z.y = z.z = z.w = 0.f;
#pragma unroll
      for (int i = 0; i < 8; ++i) h4[i * 512 + tid] = z;
    } else {
      const float4* src = (const float4*)(hbuf + (size_t)(rbuf * 2 + dir) * 16384);
#pragma unroll
      for (int i = 0; i < 8; ++i) h4[i * 512 + tid] = src[i * 512 + tid];
    }
    // prefetch xg for reducer role (used after dot loop)
    float xgv = (float)xg[((size_t)b_red * 512 + t_act) * 2048 + n_red];
    __syncthreads();

    // ---- dot: acc[ri][bi] += W_hh[row][k] * h[k][b0+bi], k in this chunk ----
    float accv[4][4];
#pragma unroll
    for (int ri = 0; ri < 4; ++ri)
#pragma unroll
      for (int bi = 0; bi < 4; ++bi) accv[ri][bi] = 0.f;
    const float* hk = smem + ks * 1024;   // (k = ks*32+kk) -> smem[k*32 + b]
#pragma unroll
    for (int kk = 0; kk < 32; ++kk) {
      float4 hv = *(const float4*)(hk + kk * 32 + b0);
#pragma unroll
      for (int ri = 0; ri < 4; ++ri) {
        float w = wreg[ri][kk];
        accv[ri][0] += w * hv.x; accv[ri][1] += w * hv.y;
        accv[ri][2] += w * hv.z; accv[ri][3] += w * hv.w;
      }
    }
    __syncthreads();   // h_s consumed; red may overwrite

    // ---- write partials to LDS ----
    float* myred = red + (size_t)(ks * 32 + mt) * 20;
#pragma unroll
    for (int ri = 0; ri < 4; ++ri) {
      float4 v;
      v.x = accv[ri][0]; v.y = accv[ri][1]; v.z = accv[ri][2]; v.w = accv[ri][3];
      *(float4*)(myred + ri * 4) = v;   // a = ri*4 + bi
    }
    __syncthreads();

    // ---- reduce across 16 k-chunks, add xg (biases folded into xg) ----
    float g = xgv;
#pragma unroll
    for (int k2 = 0; k2 < 16; ++k2) g += red[(size_t)(k2 * 32 + mt) * 20 + a_r];
    gates_s[b_red * 20 + r_red] = g;
    __syncthreads();

    // ---- cell update (threads 0..31, one batch each, 4 hidden units) ----
    if (tid < 32) {
      const int b = tid;
      const float* gv = gates_s + b * 20;
      float hout[4];
#pragma unroll
      for (int jj = 0; jj < 4; ++jj) {
        float gi = gv[jj], gf = gv[4 + jj], gg = gv[8 + jj], go = gv[12 + jj];
        float iv = 1.f / (1.f + expf(-gi));
        float fv = 1.f / (1.f + expf(-gf));
        float gz = tanhf(gg);
        float ov = 1.f / (1.f + expf(-go));
        float c  = fv * c_state[jj] + iv * gz;
        c_state[jj] = c;
        hout[jj] = ov * tanhf(c);
      }
      float4 ho4; ho4.x = hout[0]; ho4.y = hout[1]; ho4.z = hout[2]; ho4.w = hout[3];
      *(float4*)(xout + ((size_t)b * 512 + t_act) * 1024 + dir * 512 + j0) = ho4;
      float* hb = hbuf + (size_t)(((t + 1) & 1) * 2 + dir) * 16384;
#pragma unroll
      for (int jj = 0; jj < 4; ++jj) hb[(j0 + jj) * 32 + b] = hout[jj];
      // writer wave publishes its h stores to agent scope (one fence per block)
      __builtin_amdgcn_fence(__ATOMIC_RELEASE, "agent");
    }

    // ---- per-direction grid barrier (skip after final step) ----
    if (t < 511) {
      __syncthreads();
      if (tid == 0) {
        const int grp = blk & 7;                       // 16 blocks per group
        int old = __hip_atomic_fetch_add(&mybar[grp * 64], 1, __ATOMIC_RELAXED,
                                         __HIP_MEMORY_SCOPE_AGENT);
        if (old == (t + 1) * 16 - 1) {                 // last in group -> promote
          __hip_atomic_fetch_add(&mybar[512], 1, __ATOMIC_RELAXED,
                                 __HIP_MEMORY_SCOPE_AGENT);
        }
        // RELAXED poll: plain coherent load, no per-iteration cache invalidate
        while (__hip_atomic_load(&mybar[512], __ATOMIC_RELAXED,
                                 __HIP_MEMORY_SCOPE_AGENT) < (t + 1) * 8) {
          __builtin_amdgcn_s_sleep(2);
        }
      }
      __syncthreads();
      // ONE acquire fence per step: invalidate stale h lines before re-read
      __builtin_amdgcn_fence(__ATOMIC_ACQUIRE, "agent");
    }
  }
}

// ---------------------------------------------------------------------------
// 5. FC: logits[tok][c] = x2[tok] . fc_w[c] + fc_b[c]   (one wave per token)
// ---------------------------------------------------------------------------
__global__ __launch_bounds__(256) void fc_kernel(const float* __restrict__ x2,
                                                 const float* __restrict__ fc_w,
                                                 const float* __restrict__ fc_b,
                                                 float* __restrict__ logits) {
  const int wave = threadIdx.x >> 6, lane = threadIdx.x & 63;
  const int tok = blockIdx.x * 4 + wave;
  const float* xr = x2 + (size_t)tok * 1024;
  float4 xv[4];
#pragma unroll
  for (int i = 0; i < 4; ++i) xv[i] = *(const float4*)(xr + lane * 16 + i * 4);
  float out[NC];
#pragma unroll
  for (int c = 0; c < NC; ++c) {
    float acc = 0.f;
#pragma unroll
    for (int i = 0; i < 4; ++i) {
      float4 wv = *(const float4*)(fc_w + (size_t)c * 1024 + lane * 16 + i * 4);
      acc += xv[i].x * wv.x + xv[i].y * wv.y + xv[i].z * wv.z + xv[i].w * wv.w;
    }
#pragma unroll
    for (int off = 32; off >= 1; off >>= 1) acc += __shfl_down(acc, off, 64);
    out[c] = acc;
  }
  if (lane == 0) {
#pragma unroll
    for (int c = 0; c < NC; ++c) logits[(size_t)tok * NC + c] = out[c] + fc_b[c];
  }
}

// ---------------------------------------------------------------------------
// 6. CRF log-likelihood per batch (one wave per batch)
// ---------------------------------------------------------------------------
__global__ __launch_bounds__(64) void crf_kernel(const float* __restrict__ logits,
                                                 const int* __restrict__ labels,
                                                 const float* __restrict__ startv,
                                                 const float* __restrict__ endv,
                                                 const float* __restrict__ trans,
                                                 float* __restrict__ llh) {
  const int b = blockIdx.x, lane = threadIdx.x;
  const int* lab = labels + b * LL;
  const float* lg = logits + (size_t)b * LL * NC;

  // numerator (all 64 lanes strided over t)
  float part = 0.f; int cnt = 0;
  for (int t = lane; t < LL; t += 64) {
    int l = lab[t];
    int m = (l > -1);
    cnt += m;
    if (t >= 1) {
      int lp = lab[t - 1];
      int tp = (lp > -1) ? lp : 0;
      int tc = m ? l : 0;
      float v = trans[tp * NC + tc] + lg[(size_t)t * NC + tc];
      part += m ? v : 0.f;
    }
  }
#pragma unroll
  for (int off = 32; off >= 1; off >>= 1) {
    part += __shfl_down(part, off, 64);
    cnt  += __shfl_down(cnt, off, 64);
  }
  float num = 0.f;
  if (lane == 0) {
    int t0 = (lab[0] > -1) ? lab[0] : 0;
    num = startv[t0] + lg[t0] + part;
    int lastidx = cnt - 1;
    int lt = lab[lastidx]; lt = (lt > -1) ? lt : 0;
    num += endv[lt];
  }

  // forward algorithm (lanes 0..8 hold alpha_j)
  const int j = (lane < NC) ? lane : 0;
  float tr[NC];
#pragma unroll
  for (int i = 0; i < NC; ++i) tr[i] = trans[i * NC + j];
  float alpha = startv[j] + lg[j];
  for (int t = 1; t < LL; ++t) {
    float e = lg[(size_t)t * NC + j];
    float v[NC];
    float m = -3.4e38f;
#pragma unroll
    for (int i = 0; i < NC; ++i) {
      float ai = __shfl(alpha, i, 64);
      v[i] = ai + tr[i];
      m = fmaxf(m, v[i]);
    }
    float s = 0.f;
#pragma unroll
    for (int i = 0; i < NC; ++i) s += expf(v[i] - m);
    float cand = m + logf(s) + e;
    alpha = (lab[t] > -1) ? cand : alpha;
  }
  float av = alpha + endv[j];
  float vals[NC];
#pragma unroll
  for (int i = 0; i < NC; ++i) vals[i] = __shfl(av, i, 64);
  if (lane == 0) {
    float m2 = vals[0];
#pragma unroll
    for (int i = 1; i < NC; ++i) m2 = fmaxf(m2, vals[i]);
    float s2 = 0.f;
#pragma unroll
    for (int i = 0; i < NC; ++i) s2 += expf(vals[i] - m2);
    llh[b] = num - (m2 + logf(s2));
  }
}

// ---------------------------------------------------------------------------
// 7. finalize: loss = -sum(llh)
// ---------------------------------------------------------------------------
__global__ __launch_bounds__(64) void finalize_kernel(const float* __restrict__ llh,
                                                      float* __restrict__ out) {
  const int lane = threadIdx.x;
  float v = (lane < BB) ? llh[lane] : 0.f;
#pragma unroll
  for (int off = 32; off >= 1; off >>= 1) v += __shfl_down(v, off, 64);
  if (lane == 0) out[0] = -v;
}

// ---------------------------------------------------------------------------
template <typename XgT>
static void run_pipeline(const float* emb, const int* X,
                         const float* wi0, const float* wh0, const float* bi0, const float* bh0,
                         const float* wi0r, const float* wh0r, const float* bi0r, const float* bh0r,
                         const float* wi1, const float* wh1, const float* bi1, const float* bh1,
                         const float* wi1r, const float* wh1r, const float* bi1r, const float* bh1r,
                         float* x1, float* x0, XgT* xgf, XgT* xgr,
                         float* hbuf, int* bar0, int* bar1, hipStream_t stream) {
  embed_kernel<<<ML * EE / (256 * 4), 256, 0, stream>>>(X, emb, x0);
  dim3 gg(G4 / 128, ML / 128);   // (16, 128)
  gemm_bias_kernel<XgT><<<gg, 256, 0, stream>>>(x0, wi0,  bi0,  bh0,  xgf, ML, G4, EE);
  gemm_bias_kernel<XgT><<<gg, 256, 0, stream>>>(x0, wi0r, bi0r, bh0r, xgr, ML, G4, EE);
  lstm_scan_kernel<XgT><<<256, 512, 0, stream>>>(xgf, xgr, wh0, wh0r, x1, hbuf, bar0);
  gemm_bias_kernel<XgT><<<gg, 256, 0, stream>>>(x1, wi1,  bi1,  bh1,  xgf, ML, G4, 1024);
  gemm_bias_kernel<XgT><<<gg, 256, 0, stream>>>(x1, wi1r, bi1r, bh1r, xgr, ML, G4, 1024);
  lstm_scan_kernel<XgT><<<256, 512, 0, stream>>>(xgf, xgr, wh1, wh1r, x1 /*x2*/, hbuf, bar1);
}

extern "C" void kernel_launch(void* const* d_in, const int* in_sizes, int n_in,
                              void* d_out, int out_size, void* d_ws, size_t ws_size,
                              hipStream_t stream) {
  const int*   X       = (const int*)d_in[0];
  const int*   labels  = (const int*)d_in[1];
  const float* emb     = (const float*)d_in[2];
  const float* w_ih_l0  = (const float*)d_in[3];
  const float* w_hh_l0  = (const float*)d_in[4];
  const float* b_ih_l0  = (const float*)d_in[5];
  const float* b_hh_l0  = (const float*)d_in[6];
  const float* w_ih_l0r = (const float*)d_in[7];
  const float* w_hh_l0r = (const float*)d_in[8];
  const float* b_ih_l0r = (const float*)d_in[9];
  const float* b_hh_l0r = (const float*)d_in[10];
  const float* w_ih_l1  = (const float*)d_in[11];
  const float* w_hh_l1  = (const float*)d_in[12];
  const float* b_ih_l1  = (const float*)d_in[13];
  const float* b_hh_l1  = (const float*)d_in[14];
  const float* w_ih_l1r = (const float*)d_in[15];
  const float* w_hh_l1r = (const float*)d_in[16];
  const float* b_ih_l1r = (const float*)d_in[17];
  const float* b_hh_l1r = (const float*)d_in[18];
  const float* fc_w     = (const float*)d_in[19];
  const float* fc_b     = (const float*)d_in[20];
  const float* crf_start = (const float*)d_in[21];
  const float* crf_end   = (const float*)d_in[22];
  const float* crf_trans = (const float*)d_in[23];

  float* out = (float*)d_out;          // out[0]=loss, out+1 = logits [ML][9]
  const size_t MiB = 1024 * 1024;
  char* ws = (char*)d_ws;

  // x1 region: 64 MiB f32; x0 (16 MiB) aliased at its start (dead after L0 GEMMs)
  float* x1 = (float*)ws;
  float* x0 = x1;
  char* p = ws + 64 * MiB;

  const bool planA = ws_size >= 322 * MiB;
  const size_t xgBytes = planA ? 128 * MiB : 64 * MiB;
  void* xgf = (void*)p; p += xgBytes;
  void* xgr = (void*)p; p += xgBytes;
  float* hbuf = (float*)p; p += 256 * 1024;          // [2][2][512][32] f32
  int* bar0 = (int*)p; p += 8192;                    // 2 dirs x 1024 ints
  int* bar1 = (int*)p; p += 8192;
  float* llh = (float*)p; p += 4096;

  // zero the barrier counters (ws is re-poisoned to 0xAA before every launch)
  hipMemsetAsync(bar0, 0, 2 * 8192, stream);

  if (planA) {
    run_pipeline<float>(emb, X, w_ih_l0, w_hh_l0, b_ih_l0, b_hh_l0,
                        w_ih_l0r, w_hh_l0r, b_ih_l0r, b_hh_l0r,
                        w_ih_l1, w_hh_l1, b_ih_l1, b_hh_l1,
                        w_ih_l1r, w_hh_l1r, b_ih_l1r, b_hh_l1r,
                        x1, x0, (float*)xgf, (float*)xgr, hbuf, bar0, bar1, stream);
  } else {
    run_pipeline<__half>(emb, X, w_ih_l0, w_hh_l0, b_ih_l0, b_hh_l0,
                         w_ih_l0r, w_hh_l0r, b_ih_l0r, b_hh_l0r,
                         w_ih_l1, w_hh_l1, b_ih_l1, b_hh_l1,
                         w_ih_l1r, w_hh_l1r, b_ih_l1r, b_hh_l1r,
                         x1, x0, (__half*)xgf, (__half*)xgr, hbuf, bar0, bar1, stream);
  }

  fc_kernel<<<ML / 4, 256, 0, stream>>>(x1, fc_w, fc_b, out + 1);
  crf_kernel<<<BB, 64, 0, stream>>>(out + 1, labels, crf_start, crf_end, crf_trans, llh);
  finalize_kernel<<<1, 64, 0, stream>>>(llh, out);
}

// Round 5
// 18990.865 us; speedup vs baseline: 3.4663x; 1.7908x over previous
//
#include <hip/hip_runtime.h>
#include <hip/hip_fp16.h>
#include <cstdint>

// ============================================================================
// BiLSTM(2-layer, H=512) + FC + CRF NLL  — fp32 with ws-adaptive fp16 xg plan
//
// Round-5 scan design: FENCE-FREE cross-XCD h exchange.
//   - h values move via relaxed agent-scope atomic stores/loads (sc1 path,
//     coherent at Infinity Cache) -> no buffer_wbl2 / buffer_inv in the loop.
//   - Round-4 had 8 acquire fences (one per wave) + 1 release fence per block
//     per step => thousands of whole-L2 invalidate/writeback ops per step,
//     which serialized at L2 and destroyed locality (VALUBusy 4%, 31us/step).
//   - Barrier: per-direction, 8 arrival lines + 1 release line, all relaxed;
//     ordering via vmcnt drain (stores ACKed before arrival RMW issues).
// ============================================================================

#define BB 32
#define LL 512
#define EE 256
#define HH 512
#define NC 9
#define G4 2048          // 4*H
#define ML (BB*LL)       // 16384

// ---------------------------------------------------------------------------
// 1. Embedding gather
// ---------------------------------------------------------------------------
__global__ __launch_bounds__(256) void embed_kernel(const int* __restrict__ X,
                                                    const float* __restrict__ emb,
                                                    float* __restrict__ x0) {
  int gid = blockIdx.x * 256 + threadIdx.x;   // one float4 per thread
  int tok = gid >> 6;                          // 64 float4 per token (E=256)
  int e4  = gid & 63;
  int row = X[tok];
  const float4* src = (const float4*)(emb + (size_t)row * EE);
  float4* dst = (float4*)(x0 + (size_t)tok * EE);
  dst[e4] = src[e4];
}

// ---------------------------------------------------------------------------
// 2. GEMM: C[M][N] = A[M][K] @ W[N][K]^T + b1[n] + b2[n]   (OT = float | __half)
//    BM=BN=128, BK=16, 256 threads, 8x8 microtile.
// ---------------------------------------------------------------------------
__device__ inline void store8(float* p, const float* v) {
  *(float4*)p       = *(const float4*)v;
  *(float4*)(p + 4) = *(const float4*)(v + 4);
}
__device__ inline void store8(__half* p, const float* v) {
  __half h[8];
#pragma unroll
  for (int j = 0; j < 8; ++j) h[j] = __float2half(v[j]);
  *(float4*)p = *(const float4*)h;   // 16 B
}

template <typename OT>
__global__ __launch_bounds__(256) void gemm_bias_kernel(
    const float* __restrict__ A, const float* __restrict__ W,
    const float* __restrict__ b1, const float* __restrict__ b2,
    OT* __restrict__ C, int M, int N, int K) {
  __shared__ float As[16][132];
  __shared__ float Ws[16][132];
  const int tid = threadIdx.x;
  const int bn = blockIdx.x, bm = blockIdx.y;
  const int tx = tid & 15, ty = tid >> 4;

  float acc[8][8];
#pragma unroll
  for (int i = 0; i < 8; ++i)
#pragma unroll
    for (int j = 0; j < 8; ++j) acc[i][j] = 0.f;

  const int m_l = tid >> 1;            // 0..127
  const int k_l = (tid & 1) * 8;       // 0 or 8
  const float* Arow = A + (size_t)(bm * 128 + m_l) * K + k_l;
  const float* Wrow = W + (size_t)(bn * 128 + m_l) * K + k_l;

  for (int k0 = 0; k0 < K; k0 += 16) {
    float4 a0 = *(const float4*)(Arow + k0);
    float4 a1 = *(const float4*)(Arow + k0 + 4);
    float4 w0 = *(const float4*)(Wrow + k0);
    float4 w1 = *(const float4*)(Wrow + k0 + 4);
    __syncthreads();
    As[k_l + 0][m_l] = a0.x; As[k_l + 1][m_l] = a0.y;
    As[k_l + 2][m_l] = a0.z; As[k_l + 3][m_l] = a0.w;
    As[k_l + 4][m_l] = a1.x; As[k_l + 5][m_l] = a1.y;
    As[k_l + 6][m_l] = a1.z; As[k_l + 7][m_l] = a1.w;
    Ws[k_l + 0][m_l] = w0.x; Ws[k_l + 1][m_l] = w0.y;
    Ws[k_l + 2][m_l] = w0.z; Ws[k_l + 3][m_l] = w0.w;
    Ws[k_l + 4][m_l] = w1.x; Ws[k_l + 5][m_l] = w1.y;
    Ws[k_l + 6][m_l] = w1.z; Ws[k_l + 7][m_l] = w1.w;
    __syncthreads();
#pragma unroll
    for (int kk = 0; kk < 16; ++kk) {
      float4 aA = *(const float4*)&As[kk][ty * 8];
      float4 aB = *(const float4*)&As[kk][ty * 8 + 4];
      float4 wA = *(const float4*)&Ws[kk][tx * 8];
      float4 wB = *(const float4*)&Ws[kk][tx * 8 + 4];
      float av[8] = {aA.x, aA.y, aA.z, aA.w, aB.x, aB.y, aB.z, aB.w};
      float wv[8] = {wA.x, wA.y, wA.z, wA.w, wB.x, wB.y, wB.z, wB.w};
#pragma unroll
      for (int i = 0; i < 8; ++i)
#pragma unroll
        for (int j = 0; j < 8; ++j) acc[i][j] += av[i] * wv[j];
    }
  }
  const int gm = bm * 128 + ty * 8;
  const int gn = bn * 128 + tx * 8;
  float bias[8];
#pragma unroll
  for (int j = 0; j < 8; ++j) bias[j] = b1[gn + j] + b2[gn + j];
#pragma unroll
  for (int i = 0; i < 8; ++i) {
    float o8[8];
#pragma unroll
    for (int j = 0; j < 8; ++j) o8[j] = acc[i][j] + bias[j];
    store8(C + (size_t)(gm + i) * N + gn, o8);
  }
}

// ---------------------------------------------------------------------------
// 3. Persistent LSTM scan (both directions in one launch).
//    grid = 256 blocks (dir = blockIdx>>7, hidden-slice = blockIdx&127, J=4),
//    512 threads. W_hh slice in registers (4 rows x 32 k / thread).
//    h double-buffered in global [2 buf][2 dir][512 j][32 b], exchanged via
//    relaxed agent-scope atomics (coherent, L2-bypassing) -> NO fences.
// ---------------------------------------------------------------------------
template <typename XgT>
__global__ __launch_bounds__(512) void lstm_scan_kernel(
    const XgT* __restrict__ xg_f, const XgT* __restrict__ xg_r,
    const float* __restrict__ whh_f, const float* __restrict__ whh_r,
    float* __restrict__ xout,      // [ML][1024], cols dir*512 + j
    float* __restrict__ hbuf,      // [2 buf][2 dir][512 j][32 b]
    int* __restrict__ bar) {       // per dir: 1024 ints (8 grp lines + release)
  __shared__ float smem[16384];    // 64 KB: h_s [512 j][32 b]  (aliased: red+gates)
  float* red     = smem;           // [16 ks][32 mt][20]
  float* gates_s = smem + 10240;   // [32 b][20]

  const int tid = threadIdx.x;
  const int dir = blockIdx.x >> 7;
  const int blk = blockIdx.x & 127;
  const int j0  = blk * 4;
  const XgT*   xg  = dir ? xg_r  : xg_f;
  const float* whh = dir ? whh_r : whh_f;
  int* mybar = bar + dir * 1024;   // independent barrier per direction

  // dot-phase role
  const int ks   = tid >> 5;            // 0..15 (k chunk)
  const int mt   = tid & 31;            // microtile id
  const int b0   = (mt & 7) * 4;        // batch base
  const int gate = mt >> 3;             // 0..3 (i,f,g,o)

  // W_hh preload: rows gate*512 + j0 + ri, k = ks*32 + kk
  float wreg[4][32];
#pragma unroll
  for (int ri = 0; ri < 4; ++ri) {
    const float* wrow = whh + (size_t)(gate * 512 + j0 + ri) * 512 + ks * 32;
#pragma unroll
    for (int kq = 0; kq < 8; ++kq) {
      float4 v = *(const float4*)(wrow + kq * 4);
      wreg[ri][kq * 4 + 0] = v.x; wreg[ri][kq * 4 + 1] = v.y;
      wreg[ri][kq * 4 + 2] = v.z; wreg[ri][kq * 4 + 3] = v.w;
    }
  }

  // reducer role: output (b_red, r_red)
  const int a_r   = tid >> 5;                         // 0..15
  const int b_red = (mt & 7) * 4 + (a_r & 3);
  const int r_red = (mt >> 3) * 4 + (a_r >> 2);       // = gate*4 + jj
  const int n_red = (r_red >> 2) * 512 + j0 + (r_red & 3);  // xg column

  // update role (threads 0..31): c state in registers
  float c_state[4] = {0.f, 0.f, 0.f, 0.f};

#pragma unroll 1
  for (int t = 0; t < 512; ++t) {
    const int t_act = dir ? (511 - t) : t;
    const int rbuf  = t & 1;

    // ---- stage h_{t-1} into LDS ([j][b] layout) ----
    float4* h4 = (float4*)smem;
    if (t == 0) {
      float4 z; z.x = z.y = z.z = z.w = 0.f;
#pragma unroll
      for (int i = 0; i < 8; ++i) h4[i * 512 + tid] = z;
    } else {
      // coherent (sc1) relaxed atomic loads: fetch fresh h from the
      // coherence point without any cache-invalidate fence.
      const float* src = hbuf + (size_t)(rbuf * 2 + dir) * 16384;
      float hv[32];
#pragma unroll
      for (int i = 0; i < 8; ++i)
#pragma unroll
        for (int c = 0; c < 4; ++c)
          hv[i * 4 + c] = __hip_atomic_load(src + (size_t)(i * 512 + tid) * 4 + c,
                                            __ATOMIC_RELAXED, __HIP_MEMORY_SCOPE_AGENT);
#pragma unroll
      for (int i = 0; i < 8; ++i) {
        float4 v;
        v.x = hv[i * 4 + 0]; v.y = hv[i * 4 + 1];
        v.z = hv[i * 4 + 2]; v.w = hv[i * 4 + 3];
        h4[i * 512 + tid] = v;
      }
    }
    // prefetch xg for reducer role (used after dot loop)
    float xgv = (float)xg[((size_t)b_red * 512 + t_act) * 2048 + n_red];
    __syncthreads();

    // ---- dot: acc[ri][bi] += W_hh[row][k] * h[k][b0+bi], k in this chunk ----
    float accv[4][4];
#pragma unroll
    for (int ri = 0; ri < 4; ++ri)
#pragma unroll
      for (int bi = 0; bi < 4; ++bi) accv[ri][bi] = 0.f;
    const float* hk = smem + ks * 1024;   // (k = ks*32+kk) -> smem[k*32 + b]
#pragma unroll
    for (int kk = 0; kk < 32; ++kk) {
      float4 hv = *(const float4*)(hk + kk * 32 + b0);
#pragma unroll
      for (int ri = 0; ri < 4; ++ri) {
        float w = wreg[ri][kk];
        accv[ri][0] += w * hv.x; accv[ri][1] += w * hv.y;
        accv[ri][2] += w * hv.z; accv[ri][3] += w * hv.w;
      }
    }
    __syncthreads();   // h_s consumed; red may overwrite

    // ---- write partials to LDS ----
    float* myred = red + (size_t)(ks * 32 + mt) * 20;
#pragma unroll
    for (int ri = 0; ri < 4; ++ri) {
      float4 v;
      v.x = accv[ri][0]; v.y = accv[ri][1]; v.z = accv[ri][2]; v.w = accv[ri][3];
      *(float4*)(myred + ri * 4) = v;   // a = ri*4 + bi
    }
    __syncthreads();

    // ---- reduce across 16 k-chunks, add xg (biases folded into xg) ----
    float g = xgv;
#pragma unroll
    for (int k2 = 0; k2 < 16; ++k2) g += red[(size_t)(k2 * 32 + mt) * 20 + a_r];
    gates_s[b_red * 20 + r_red] = g;
    __syncthreads();

    // ---- cell update (threads 0..31, one batch each, 4 hidden units) ----
    if (tid < 32) {
      const int b = tid;
      const float* gv = gates_s + b * 20;
      float hout[4];
#pragma unroll
      for (int jj = 0; jj < 4; ++jj) {
        float gi = gv[jj], gf = gv[4 + jj], gg = gv[8 + jj], go = gv[12 + jj];
        float iv = 1.f / (1.f + expf(-gi));
        float fv = 1.f / (1.f + expf(-gf));
        float gz = tanhf(gg);
        float ov = 1.f / (1.f + expf(-go));
        float c  = fv * c_state[jj] + iv * gz;
        c_state[jj] = c;
        hout[jj] = ov * tanhf(c);
      }
      float4 ho4; ho4.x = hout[0]; ho4.y = hout[1]; ho4.z = hout[2]; ho4.w = hout[3];
      *(float4*)(xout + ((size_t)b * 512 + t_act) * 1024 + dir * 512 + j0) = ho4;
      // coherent (sc1) relaxed atomic stores: land at the coherence point,
      // visible to all XCDs' sc1 loads without any writeback fence.
      float* hb = hbuf + (size_t)(((t + 1) & 1) * 2 + dir) * 16384;
#pragma unroll
      for (int jj = 0; jj < 4; ++jj)
        __hip_atomic_store(hb + (j0 + jj) * 32 + b, hout[jj],
                           __ATOMIC_RELAXED, __HIP_MEMORY_SCOPE_AGENT);
      // drain: stores ACKed at coherence point before this wave hits the
      // barrier (so the arrival RMW below is ordered after them)
      asm volatile("s_waitcnt vmcnt(0)" ::: "memory");
    }

    // ---- per-direction grid barrier (skip after final step) ----
    if (t < 511) {
      __syncthreads();
      if (tid == 0) {
        const int grp = blk & 7;                       // 16 blocks per group
        int old = __hip_atomic_fetch_add(&mybar[grp * 64], 1, __ATOMIC_RELAXED,
                                         __HIP_MEMORY_SCOPE_AGENT);
        if (old == (t + 1) * 16 - 1) {                 // last in group -> promote
          __hip_atomic_fetch_add(&mybar[512], 1, __ATOMIC_RELAXED,
                                 __HIP_MEMORY_SCOPE_AGENT);
        }
        // relaxed poll: plain coherent load, no cache maintenance
        while (__hip_atomic_load(&mybar[512], __ATOMIC_RELAXED,
                                 __HIP_MEMORY_SCOPE_AGENT) < (t + 1) * 8) {
          __builtin_amdgcn_s_sleep(1);
        }
      }
      __syncthreads();
    }
  }
}

// ---------------------------------------------------------------------------
// 5. FC: logits[tok][c] = x2[tok] . fc_w[c] + fc_b[c]   (one wave per token)
// ---------------------------------------------------------------------------
__global__ __launch_bounds__(256) void fc_kernel(const float* __restrict__ x2,
                                                 const float* __restrict__ fc_w,
                                                 const float* __restrict__ fc_b,
                                                 float* __restrict__ logits) {
  const int wave = threadIdx.x >> 6, lane = threadIdx.x & 63;
  const int tok = blockIdx.x * 4 + wave;
  const float* xr = x2 + (size_t)tok * 1024;
  float4 xv[4];
#pragma unroll
  for (int i = 0; i < 4; ++i) xv[i] = *(const float4*)(xr + lane * 16 + i * 4);
  float out[NC];
#pragma unroll
  for (int c = 0; c < NC; ++c) {
    float acc = 0.f;
#pragma unroll
    for (int i = 0; i < 4; ++i) {
      float4 wv = *(const float4*)(fc_w + (size_t)c * 1024 + lane * 16 + i * 4);
      acc += xv[i].x * wv.x + xv[i].y * wv.y + xv[i].z * wv.z + xv[i].w * wv.w;
    }
#pragma unroll
    for (int off = 32; off >= 1; off >>= 1) acc += __shfl_down(acc, off, 64);
    out[c] = acc;
  }
  if (lane == 0) {
#pragma unroll
    for (int c = 0; c < NC; ++c) logits[(size_t)tok * NC + c] = out[c] + fc_b[c];
  }
}

// ---------------------------------------------------------------------------
// 6. CRF log-likelihood per batch (one wave per batch)
// ---------------------------------------------------------------------------
__global__ __launch_bounds__(64) void crf_kernel(const float* __restrict__ logits,
                                                 const int* __restrict__ labels,
                                                 const float* __restrict__ startv,
                                                 const float* __restrict__ endv,
                                                 const float* __restrict__ trans,
                                                 float* __restrict__ llh) {
  const int b = blockIdx.x, lane = threadIdx.x;
  const int* lab = labels + b * LL;
  const float* lg = logits + (size_t)b * LL * NC;

  // numerator (all 64 lanes strided over t)
  float part = 0.f; int cnt = 0;
  for (int t = lane; t < LL; t += 64) {
    int l = lab[t];
    int m = (l > -1);
    cnt += m;
    if (t >= 1) {
      int lp = lab[t - 1];
      int tp = (lp > -1) ? lp : 0;
      int tc = m ? l : 0;
      float v = trans[tp * NC + tc] + lg[(size_t)t * NC + tc];
      part += m ? v : 0.f;
    }
  }
#pragma unroll
  for (int off = 32; off >= 1; off >>= 1) {
    part += __shfl_down(part, off, 64);
    cnt  += __shfl_down(cnt, off, 64);
  }
  float num = 0.f;
  if (lane == 0) {
    int t0 = (lab[0] > -1) ? lab[0] : 0;
    num = startv[t0] + lg[t0] + part;
    int lastidx = cnt - 1;
    int lt = lab[lastidx]; lt = (lt > -1) ? lt : 0;
    num += endv[lt];
  }

  // forward algorithm (lanes 0..8 hold alpha_j)
  const int j = (lane < NC) ? lane : 0;
  float tr[NC];
#pragma unroll
  for (int i = 0; i < NC; ++i) tr[i] = trans[i * NC + j];
  float alpha = startv[j] + lg[j];
  for (int t = 1; t < LL; ++t) {
    float e = lg[(size_t)t * NC + j];
    float v[NC];
    float m = -3.4e38f;
#pragma unroll
    for (int i = 0; i < NC; ++i) {
      float ai = __shfl(alpha, i, 64);
      v[i] = ai + tr[i];
      m = fmaxf(m, v[i]);
    }
    float s = 0.f;
#pragma unroll
    for (int i = 0; i < NC; ++i) s += expf(v[i] - m);
    float cand = m + logf(s) + e;
    alpha = (lab[t] > -1) ? cand : alpha;
  }
  float av = alpha + endv[j];
  float vals[NC];
#pragma unroll
  for (int i = 0; i < NC; ++i) vals[i] = __shfl(av, i, 64);
  if (lane == 0) {
    float m2 = vals[0];
#pragma unroll
    for (int i = 1; i < NC; ++i) m2 = fmaxf(m2, vals[i]);
    float s2 = 0.f;
#pragma unroll
    for (int i = 0; i < NC; ++i) s2 += expf(vals[i] - m2);
    llh[b] = num - (m2 + logf(s2));
  }
}

// ---------------------------------------------------------------------------
// 7. finalize: loss = -sum(llh)
// ---------------------------------------------------------------------------
__global__ __launch_bounds__(64) void finalize_kernel(const float* __restrict__ llh,
                                                      float* __restrict__ out) {
  const int lane = threadIdx.x;
  float v = (lane < BB) ? llh[lane] : 0.f;
#pragma unroll
  for (int off = 32; off >= 1; off >>= 1) v += __shfl_down(v, off, 64);
  if (lane == 0) out[0] = -v;
}

// ---------------------------------------------------------------------------
template <typename XgT>
static void run_pipeline(const float* emb, const int* X,
                         const float* wi0, const float* wh0, const float* bi0, const float* bh0,
                         const float* wi0r, const float* wh0r, const float* bi0r, const float* bh0r,
                         const float* wi1, const float* wh1, const float* bi1, const float* bh1,
                         const float* wi1r, const float* wh1r, const float* bi1r, const float* bh1r,
                         float* x1, float* x0, XgT* xgf, XgT* xgr,
                         float* hbuf, int* bar0, int* bar1, hipStream_t stream) {
  embed_kernel<<<ML * EE / (256 * 4), 256, 0, stream>>>(X, emb, x0);
  dim3 gg(G4 / 128, ML / 128);   // (16, 128)
  gemm_bias_kernel<XgT><<<gg, 256, 0, stream>>>(x0, wi0,  bi0,  bh0,  xgf, ML, G4, EE);
  gemm_bias_kernel<XgT><<<gg, 256, 0, stream>>>(x0, wi0r, bi0r, bh0r, xgr, ML, G4, EE);
  lstm_scan_kernel<XgT><<<256, 512, 0, stream>>>(xgf, xgr, wh0, wh0r, x1, hbuf, bar0);
  gemm_bias_kernel<XgT><<<gg, 256, 0, stream>>>(x1, wi1,  bi1,  bh1,  xgf, ML, G4, 1024);
  gemm_bias_kernel<XgT><<<gg, 256, 0, stream>>>(x1, wi1r, bi1r, bh1r, xgr, ML, G4, 1024);
  lstm_scan_kernel<XgT><<<256, 512, 0, stream>>>(xgf, xgr, wh1, wh1r, x1 /*x2*/, hbuf, bar1);
}

extern "C" void kernel_launch(void* const* d_in, const int* in_sizes, int n_in,
                              void* d_out, int out_size, void* d_ws, size_t ws_size,
                              hipStream_t stream) {
  const int*   X       = (const int*)d_in[0];
  const int*   labels  = (const int*)d_in[1];
  const float* emb     = (const float*)d_in[2];
  const float* w_ih_l0  = (const float*)d_in[3];
  const float* w_hh_l0  = (const float*)d_in[4];
  const float* b_ih_l0  = (const float*)d_in[5];
  const float* b_hh_l0  = (const float*)d_in[6];
  const float* w_ih_l0r = (const float*)d_in[7];
  const float* w_hh_l0r = (const float*)d_in[8];
  const float* b_ih_l0r = (const float*)d_in[9];
  const float* b_hh_l0r = (const float*)d_in[10];
  const float* w_ih_l1  = (const float*)d_in[11];
  const float* w_hh_l1  = (const float*)d_in[12];
  const float* b_ih_l1  = (const float*)d_in[13];
  const float* b_hh_l1  = (const float*)d_in[14];
  const float* w_ih_l1r = (const float*)d_in[15];
  const float* w_hh_l1r = (const float*)d_in[16];
  const float* b_ih_l1r = (const float*)d_in[17];
  const float* b_hh_l1r = (const float*)d_in[18];
  const float* fc_w     = (const float*)d_in[19];
  const float* fc_b     = (const float*)d_in[20];
  const float* crf_start = (const float*)d_in[21];
  const float* crf_end   = (const float*)d_in[22];
  const float* crf_trans = (const float*)d_in[23];

  float* out = (float*)d_out;          // out[0]=loss, out+1 = logits [ML][9]
  const size_t MiB = 1024 * 1024;
  char* ws = (char*)d_ws;

  // x1 region: 64 MiB f32; x0 (16 MiB) aliased at its start (dead after L0 GEMMs)
  float* x1 = (float*)ws;
  float* x0 = x1;
  char* p = ws + 64 * MiB;

  const bool planA = ws_size >= 322 * MiB;
  const size_t xgBytes = planA ? 128 * MiB : 64 * MiB;
  void* xgf = (void*)p; p += xgBytes;
  void* xgr = (void*)p; p += xgBytes;
  float* hbuf = (float*)p; p += 256 * 1024;          // [2][2][512][32] f32
  int* bar0 = (int*)p; p += 8192;                    // 2 dirs x 1024 ints
  int* bar1 = (int*)p; p += 8192;
  float* llh = (float*)p; p += 4096;

  // zero the barrier counters (ws is re-poisoned to 0xAA before every launch)
  hipMemsetAsync(bar0, 0, 2 * 8192, stream);

  if (planA) {
    run_pipeline<float>(emb, X, w_ih_l0, w_hh_l0, b_ih_l0, b_hh_l0,
                        w_ih_l0r, w_hh_l0r, b_ih_l0r, b_hh_l0r,
                        w_ih_l1, w_hh_l1, b_ih_l1, b_hh_l1,
                        w_ih_l1r, w_hh_l1r, b_ih_l1r, b_hh_l1r,
                        x1, x0, (float*)xgf, (float*)xgr, hbuf, bar0, bar1, stream);
  } else {
    run_pipeline<__half>(emb, X, w_ih_l0, w_hh_l0, b_ih_l0, b_hh_l0,
                         w_ih_l0r, w_hh_l0r, b_ih_l0r, b_hh_l0r,
                         w_ih_l1, w_hh_l1, b_ih_l1, b_hh_l1,
                         w_ih_l1r, w_hh_l1r, b_ih_l1r, b_hh_l1r,
                         x1, x0, (__half*)xgf, (__half*)xgr, hbuf, bar0, bar1, stream);
  }

  fc_kernel<<<ML / 4, 256, 0, stream>>>(x1, fc_w, fc_b, out + 1);
  crf_kernel<<<BB, 64, 0, stream>>>(out + 1, labels, crf_start, crf_end, crf_trans, llh);
  finalize_kernel<<<1, 64, 0, stream>>>(llh, out);
}

// Round 6
// 9471.218 us; speedup vs baseline: 6.9502x; 2.0051x over previous
//
#include <hip/hip_runtime.h>
#include <hip/hip_fp16.h>
#include <cstdint>

// ============================================================================
// BiLSTM(2-layer, H=512) + FC + CRF NLL
//
// Round-6 scan: 2D decomposition (batch-group x j-block) to shrink the
// all-to-all h exchange 8x in bytes / 16x in transactions.
//   grid 256 = dir(2) x bgroup(8, 4 batches each) x jblock(16, 32 j each)
//   - groups of 16 blocks exchange h[512j][4b] = 8 KB/step via 64-bit
//     agent-scope relaxed atomics (proven primitive from round 5)
//   - W_hh slice (4 gates x 32 j x 512 k / block) stays in VGPRs
//   - flat 16-arrival barrier per group, relaxed atomics, no fences
//   - xg reads become 32-consecutive-column clusters (line-exact, kills the
//     round-5 23x HBM over-fetch that showed as FETCH_SIZE=3GB)
// ============================================================================

#define BB 32
#define LL 512
#define EE 256
#define HH 512
#define NC 9
#define G4 2048          // 4*H
#define ML (BB*LL)       // 16384

// ---------------------------------------------------------------------------
// 1. Embedding gather
// ---------------------------------------------------------------------------
__global__ __launch_bounds__(256) void embed_kernel(const int* __restrict__ X,
                                                    const float* __restrict__ emb,
                                                    float* __restrict__ x0) {
  int gid = blockIdx.x * 256 + threadIdx.x;   // one float4 per thread
  int tok = gid >> 6;                          // 64 float4 per token (E=256)
  int e4  = gid & 63;
  int row = X[tok];
  const float4* src = (const float4*)(emb + (size_t)row * EE);
  float4* dst = (float4*)(x0 + (size_t)tok * EE);
  dst[e4] = src[e4];
}

// ---------------------------------------------------------------------------
// 2. GEMM: C[M][N] = A[M][K] @ W[N][K]^T + b1[n] + b2[n]   (OT = float | __half)
// ---------------------------------------------------------------------------
__device__ inline void store8(float* p, const float* v) {
  *(float4*)p       = *(const float4*)v;
  *(float4*)(p + 4) = *(const float4*)(v + 4);
}
__device__ inline void store8(__half* p, const float* v) {
  __half h[8];
#pragma unroll
  for (int j = 0; j < 8; ++j) h[j] = __float2half(v[j]);
  *(float4*)p = *(const float4*)h;   // 16 B
}

template <typename OT>
__global__ __launch_bounds__(256) void gemm_bias_kernel(
    const float* __restrict__ A, const float* __restrict__ W,
    const float* __restrict__ b1, const float* __restrict__ b2,
    OT* __restrict__ C, int M, int N, int K) {
  __shared__ float As[16][132];
  __shared__ float Ws[16][132];
  const int tid = threadIdx.x;
  const int bn = blockIdx.x, bm = blockIdx.y;
  const int tx = tid & 15, ty = tid >> 4;

  float acc[8][8];
#pragma unroll
  for (int i = 0; i < 8; ++i)
#pragma unroll
    for (int j = 0; j < 8; ++j) acc[i][j] = 0.f;

  const int m_l = tid >> 1;            // 0..127
  const int k_l = (tid & 1) * 8;       // 0 or 8
  const float* Arow = A + (size_t)(bm * 128 + m_l) * K + k_l;
  const float* Wrow = W + (size_t)(bn * 128 + m_l) * K + k_l;

  for (int k0 = 0; k0 < K; k0 += 16) {
    float4 a0 = *(const float4*)(Arow + k0);
    float4 a1 = *(const float4*)(Arow + k0 + 4);
    float4 w0 = *(const float4*)(Wrow + k0);
    float4 w1 = *(const float4*)(Wrow + k0 + 4);
    __syncthreads();
    As[k_l + 0][m_l] = a0.x; As[k_l + 1][m_l] = a0.y;
    As[k_l + 2][m_l] = a0.z; As[k_l + 3][m_l] = a0.w;
    As[k_l + 4][m_l] = a1.x; As[k_l + 5][m_l] = a1.y;
    As[k_l + 6][m_l] = a1.z; As[k_l + 7][m_l] = a1.w;
    Ws[k_l + 0][m_l] = w0.x; Ws[k_l + 1][m_l] = w0.y;
    Ws[k_l + 2][m_l] = w0.z; Ws[k_l + 3][m_l] = w0.w;
    Ws[k_l + 4][m_l] = w1.x; Ws[k_l + 5][m_l] = w1.y;
    Ws[k_l + 6][m_l] = w1.z; Ws[k_l + 7][m_l] = w1.w;
    __syncthreads();
#pragma unroll
    for (int kk = 0; kk < 16; ++kk) {
      float4 aA = *(const float4*)&As[kk][ty * 8];
      float4 aB = *(const float4*)&As[kk][ty * 8 + 4];
      float4 wA = *(const float4*)&Ws[kk][tx * 8];
      float4 wB = *(const float4*)&Ws[kk][tx * 8 + 4];
      float av[8] = {aA.x, aA.y, aA.z, aA.w, aB.x, aB.y, aB.z, aB.w};
      float wv[8] = {wA.x, wA.y, wA.z, wA.w, wB.x, wB.y, wB.z, wB.w};
#pragma unroll
      for (int i = 0; i < 8; ++i)
#pragma unroll
        for (int j = 0; j < 8; ++j) acc[i][j] += av[i] * wv[j];
    }
  }
  const int gm = bm * 128 + ty * 8;
  const int gn = bn * 128 + tx * 8;
  float bias[8];
#pragma unroll
  for (int j = 0; j < 8; ++j) bias[j] = b1[gn + j] + b2[gn + j];
#pragma unroll
  for (int i = 0; i < 8; ++i) {
    float o8[8];
#pragma unroll
    for (int j = 0; j < 8; ++j) o8[j] = acc[i][j] + bias[j];
    store8(C + (size_t)(gm + i) * N + gn, o8);
  }
}

// ---------------------------------------------------------------------------
// 3. Persistent LSTM scan.
//    blockIdx = dir*128 + bg*16 + jb.  Each block: 4 gates x 32 j x 4 batches.
//    Group (dir,bg) = 16 blocks sharing h[512][4] (8 KB) per step.
//    hbuf layout: [buf2][dir2][bg8][2048 floats], group slice linear
//    ([jb][jj][b] = jb*128 + jj*4 + b).
// ---------------------------------------------------------------------------
template <typename XgT>
__global__ __launch_bounds__(512) void lstm_scan_kernel(
    const XgT* __restrict__ xg_f, const XgT* __restrict__ xg_r,
    const float* __restrict__ whh_f, const float* __restrict__ whh_r,
    float* __restrict__ xout,      // [ML][1024], cols dir*512 + j
    float* __restrict__ hbuf,      // [2][2][8][2048] floats
    int* __restrict__ bar) {       // 16 groups x 64-int lines
  __shared__ float smem[10752];    // h_s[2048] | red[8192] | gates_s[512]
  float* red     = smem + 2048;    // [16 ks][512]  (flat: ks*512 + mt*16 + ri*4 + bi)
  float* gates_s = smem + 10240;   // [128 cell][4 gate]

  const int tid = threadIdx.x;
  const int bx  = blockIdx.x;
  const int dir = bx >> 7;
  const int bg  = (bx >> 4) & 7;
  const int jb  = bx & 15;
  const int gid = bx >> 4;              // dir*8 + bg
  const int j0  = jb * 32;
  const int b_base = bg * 4;
  const XgT*   xg  = dir ? xg_r  : xg_f;
  const float* whh = dir ? whh_r : whh_f;
  int* mybar = bar + gid * 64;

  const int ks = tid >> 5;              // 0..15 k-chunk
  const int mt = tid & 31;              // row-group (4 rows each)

  // W_hh slice in registers: rows row_local = mt*4+ri -> (g = rl>>5, jj = rl&31)
  float wreg[4][32];
#pragma unroll
  for (int ri = 0; ri < 4; ++ri) {
    const int rl = mt * 4 + ri;
    const float* wrow = whh + (size_t)((rl >> 5) * 512 + j0 + (rl & 31)) * 512 + ks * 32;
#pragma unroll
    for (int kq = 0; kq < 8; ++kq) {
      float4 v = *(const float4*)(wrow + kq * 4);
      wreg[ri][kq * 4 + 0] = v.x; wreg[ri][kq * 4 + 1] = v.y;
      wreg[ri][kq * 4 + 2] = v.z; wreg[ri][kq * 4 + 3] = v.w;
    }
  }

  // reduce-role constants: output o = tid -> (row_local = tid>>2, b = tid&3)
  const int r_row = tid >> 2;
  const int r_b   = tid & 3;
  const size_t xg_col = (size_t)(r_row >> 5) * 512 + j0 + (r_row & 31);
  const int cell_o = ((r_row & 31) * 4 + r_b) * 4 + (r_row >> 5);  // gates_s idx

  // update-role (tid<64): cells 2*tid, 2*tid+1  (jj = tid>>1, b = (tid&1)*2 +{0,1})
  float cs0 = 0.f, cs1 = 0.f;

#pragma unroll 1
  for (int t = 0; t < 512; ++t) {
    const int t_act = dir ? (511 - t) : t;

    // ---- stage group h slice (2048 floats) into LDS ----
    if (t == 0) {
      float4 z; z.x = z.y = z.z = z.w = 0.f;
      ((float4*)smem)[tid] = z;
    } else {
      const unsigned long long* src = (const unsigned long long*)
          (hbuf + ((size_t)((t & 1) * 2 + dir) * 8 + bg) * 2048);
      unsigned long long v0 = __hip_atomic_load(src + tid, __ATOMIC_RELAXED,
                                                __HIP_MEMORY_SCOPE_AGENT);
      unsigned long long v1 = __hip_atomic_load(src + tid + 512, __ATOMIC_RELAXED,
                                                __HIP_MEMORY_SCOPE_AGENT);
      float2* s2 = (float2*)smem;
      union { unsigned long long u; float2 f; } c0, c1;
      c0.u = v0; c1.u = v1;
      s2[tid] = c0.f;
      s2[tid + 512] = c1.f;
    }
    // prefetch xg (consumed in reduce phase)
    float xgv = (float)xg[((size_t)(b_base + r_b) * 512 + t_act) * 2048 + xg_col];
    __syncthreads();

    // ---- dot: accv[ri][bi] += W[rl][k] * h[k][bi]  (h read = wave broadcast) ----
    float accv[4][4];
#pragma unroll
    for (int ri = 0; ri < 4; ++ri)
#pragma unroll
      for (int bi = 0; bi < 4; ++bi) accv[ri][bi] = 0.f;
    const float4* h4 = (const float4*)smem;
#pragma unroll
    for (int kk = 0; kk < 32; ++kk) {
      float4 hv = h4[ks * 32 + kk];
#pragma unroll
      for (int ri = 0; ri < 4; ++ri) {
        float w = wreg[ri][kk];
        accv[ri][0] += w * hv.x; accv[ri][1] += w * hv.y;
        accv[ri][2] += w * hv.z; accv[ri][3] += w * hv.w;
      }
    }

    // ---- write partials (disjoint region from h_s; no sync needed before) ----
    float* myred = red + ks * 512 + mt * 16;
#pragma unroll
    for (int ri = 0; ri < 4; ++ri) {
      float4 v;
      v.x = accv[ri][0]; v.y = accv[ri][1]; v.z = accv[ri][2]; v.w = accv[ri][3];
      *(float4*)(myred + ri * 4) = v;
    }
    __syncthreads();

    // ---- reduce 16 k-chunks + xg, scatter to gates_s[cell][gate] ----
    float g = xgv;
#pragma unroll
    for (int k2 = 0; k2 < 16; ++k2) g += red[k2 * 512 + tid];
    gates_s[cell_o] = g;
    __syncthreads();

    // ---- cell update: tid<64, two cells each ----
    if (tid < 64) {
      const int c0i = 2 * tid, c1i = 2 * tid + 1;
      float gi0 = gates_s[c0i * 4 + 0], gf0 = gates_s[c0i * 4 + 1];
      float gg0 = gates_s[c0i * 4 + 2], go0 = gates_s[c0i * 4 + 3];
      float gi1 = gates_s[c1i * 4 + 0], gf1 = gates_s[c1i * 4 + 1];
      float gg1 = gates_s[c1i * 4 + 2], go1 = gates_s[c1i * 4 + 3];
      float i0 = 1.f / (1.f + expf(-gi0)), f0 = 1.f / (1.f + expf(-gf0));
      float z0 = tanhf(gg0),              o0 = 1.f / (1.f + expf(-go0));
      float i1 = 1.f / (1.f + expf(-gi1)), f1 = 1.f / (1.f + expf(-gf1));
      float z1 = tanhf(gg1),              o1 = 1.f / (1.f + expf(-go1));
      cs0 = f0 * cs0 + i0 * z0;
      cs1 = f1 * cs1 + i1 * z1;
      float h0 = o0 * tanhf(cs0);
      float h1 = o1 * tanhf(cs1);

      // publish h pair (8B) to coherence point
      union { float f[2]; unsigned long long u; } pk;
      pk.f[0] = h0; pk.f[1] = h1;
      unsigned long long* hbn = (unsigned long long*)
          (hbuf + ((size_t)(((t + 1) & 1) * 2 + dir) * 8 + bg) * 2048 + jb * 128);
      __hip_atomic_store(hbn + tid, pk.u, __ATOMIC_RELAXED,
                         __HIP_MEMORY_SCOPE_AGENT);

      // xout: cells (jj = tid>>1, b = (tid&1)*2 + {0,1})
      const int jj = tid >> 1, bp = (tid & 1) * 2;
      xout[((size_t)(b_base + bp)     * 512 + t_act) * 1024 + dir * 512 + j0 + jj] = h0;
      xout[((size_t)(b_base + bp + 1) * 512 + t_act) * 1024 + dir * 512 + j0 + jj] = h1;
    }

    // ---- per-group barrier (16 blocks), flat counter, relaxed ----
    if (t < 511) {
      __syncthreads();                 // implies waitcnt: stores ACKed
      if (tid == 0) {
        __hip_atomic_fetch_add(mybar, 1, __ATOMIC_RELAXED,
                               __HIP_MEMORY_SCOPE_AGENT);
        while (__hip_atomic_load(mybar, __ATOMIC_RELAXED,
                                 __HIP_MEMORY_SCOPE_AGENT) < (t + 1) * 16) {
          __builtin_amdgcn_s_sleep(1);
        }
      }
      __syncthreads();
    }
  }
}

// ---------------------------------------------------------------------------
// 5. FC: logits[tok][c] = x2[tok] . fc_w[c] + fc_b[c]   (one wave per token)
// ---------------------------------------------------------------------------
__global__ __launch_bounds__(256) void fc_kernel(const float* __restrict__ x2,
                                                 const float* __restrict__ fc_w,
                                                 const float* __restrict__ fc_b,
                                                 float* __restrict__ logits) {
  const int wave = threadIdx.x >> 6, lane = threadIdx.x & 63;
  const int tok = blockIdx.x * 4 + wave;
  const float* xr = x2 + (size_t)tok * 1024;
  float4 xv[4];
#pragma unroll
  for (int i = 0; i < 4; ++i) xv[i] = *(const float4*)(xr + lane * 16 + i * 4);
  float out[NC];
#pragma unroll
  for (int c = 0; c < NC; ++c) {
    float acc = 0.f;
#pragma unroll
    for (int i = 0; i < 4; ++i) {
      float4 wv = *(const float4*)(fc_w + (size_t)c * 1024 + lane * 16 + i * 4);
      acc += xv[i].x * wv.x + xv[i].y * wv.y + xv[i].z * wv.z + xv[i].w * wv.w;
    }
#pragma unroll
    for (int off = 32; off >= 1; off >>= 1) acc += __shfl_down(acc, off, 64);
    out[c] = acc;
  }
  if (lane == 0) {
#pragma unroll
    for (int c = 0; c < NC; ++c) logits[(size_t)tok * NC + c] = out[c] + fc_b[c];
  }
}

// ---------------------------------------------------------------------------
// 6. CRF log-likelihood per batch (one wave per batch)
// ---------------------------------------------------------------------------
__global__ __launch_bounds__(64) void crf_kernel(const float* __restrict__ logits,
                                                 const int* __restrict__ labels,
                                                 const float* __restrict__ startv,
                                                 const float* __restrict__ endv,
                                                 const float* __restrict__ trans,
                                                 float* __restrict__ llh) {
  const int b = blockIdx.x, lane = threadIdx.x;
  const int* lab = labels + b * LL;
  const float* lg = logits + (size_t)b * LL * NC;

  // numerator (all 64 lanes strided over t)
  float part = 0.f; int cnt = 0;
  for (int t = lane; t < LL; t += 64) {
    int l = lab[t];
    int m = (l > -1);
    cnt += m;
    if (t >= 1) {
      int lp = lab[t - 1];
      int tp = (lp > -1) ? lp : 0;
      int tc = m ? l : 0;
      float v = trans[tp * NC + tc] + lg[(size_t)t * NC + tc];
      part += m ? v : 0.f;
    }
  }
#pragma unroll
  for (int off = 32; off >= 1; off >>= 1) {
    part += __shfl_down(part, off, 64);
    cnt  += __shfl_down(cnt, off, 64);
  }
  float num = 0.f;
  if (lane == 0) {
    int t0 = (lab[0] > -1) ? lab[0] : 0;
    num = startv[t0] + lg[t0] + part;
    int lastidx = cnt - 1;
    int lt = lab[lastidx]; lt = (lt > -1) ? lt : 0;
    num += endv[lt];
  }

  // forward algorithm (lanes 0..8 hold alpha_j)
  const int j = (lane < NC) ? lane : 0;
  float tr[NC];
#pragma unroll
  for (int i = 0; i < NC; ++i) tr[i] = trans[i * NC + j];
  float alpha = startv[j] + lg[j];
  for (int t = 1; t < LL; ++t) {
    float e = lg[(size_t)t * NC + j];
    float v[NC];
    float m = -3.4e38f;
#pragma unroll
    for (int i = 0; i < NC; ++i) {
      float ai = __shfl(alpha, i, 64);
      v[i] = ai + tr[i];
      m = fmaxf(m, v[i]);
    }
    float s = 0.f;
#pragma unroll
    for (int i = 0; i < NC; ++i) s += expf(v[i] - m);
    float cand = m + logf(s) + e;
    alpha = (lab[t] > -1) ? cand : alpha;
  }
  float av = alpha + endv[j];
  float vals[NC];
#pragma unroll
  for (int i = 0; i < NC; ++i) vals[i] = __shfl(av, i, 64);
  if (lane == 0) {
    float m2 = vals[0];
#pragma unroll
    for (int i = 1; i < NC; ++i) m2 = fmaxf(m2, vals[i]);
    float s2 = 0.f;
#pragma unroll
    for (int i = 0; i < NC; ++i) s2 += expf(vals[i] - m2);
    llh[b] = num - (m2 + logf(s2));
  }
}

// ---------------------------------------------------------------------------
// 7. finalize: loss = -sum(llh)
// ---------------------------------------------------------------------------
__global__ __launch_bounds__(64) void finalize_kernel(const float* __restrict__ llh,
                                                      float* __restrict__ out) {
  const int lane = threadIdx.x;
  float v = (lane < BB) ? llh[lane] : 0.f;
#pragma unroll
  for (int off = 32; off >= 1; off >>= 1) v += __shfl_down(v, off, 64);
  if (lane == 0) out[0] = -v;
}

// ---------------------------------------------------------------------------
template <typename XgT>
static void run_pipeline(const float* emb, const int* X,
                         const float* wi0, const float* wh0, const float* bi0, const float* bh0,
                         const float* wi0r, const float* wh0r, const float* bi0r, const float* bh0r,
                         const float* wi1, const float* wh1, const float* bi1, const float* bh1,
                         const float* wi1r, const float* wh1r, const float* bi1r, const float* bh1r,
                         float* x1, float* x0, XgT* xgf, XgT* xgr,
                         float* hbuf, int* bar0, int* bar1, hipStream_t stream) {
  embed_kernel<<<ML * EE / (256 * 4), 256, 0, stream>>>(X, emb, x0);
  dim3 gg(G4 / 128, ML / 128);   // (16, 128)
  gemm_bias_kernel<XgT><<<gg, 256, 0, stream>>>(x0, wi0,  bi0,  bh0,  xgf, ML, G4, EE);
  gemm_bias_kernel<XgT><<<gg, 256, 0, stream>>>(x0, wi0r, bi0r, bh0r, xgr, ML, G4, EE);
  lstm_scan_kernel<XgT><<<256, 512, 0, stream>>>(xgf, xgr, wh0, wh0r, x1, hbuf, bar0);
  gemm_bias_kernel<XgT><<<gg, 256, 0, stream>>>(x1, wi1,  bi1,  bh1,  xgf, ML, G4, 1024);
  gemm_bias_kernel<XgT><<<gg, 256, 0, stream>>>(x1, wi1r, bi1r, bh1r, xgr, ML, G4, 1024);
  lstm_scan_kernel<XgT><<<256, 512, 0, stream>>>(xgf, xgr, wh1, wh1r, x1 /*x2*/, hbuf, bar1);
}

extern "C" void kernel_launch(void* const* d_in, const int* in_sizes, int n_in,
                              void* d_out, int out_size, void* d_ws, size_t ws_size,
                              hipStream_t stream) {
  const int*   X       = (const int*)d_in[0];
  const int*   labels  = (const int*)d_in[1];
  const float* emb     = (const float*)d_in[2];
  const float* w_ih_l0  = (const float*)d_in[3];
  const float* w_hh_l0  = (const float*)d_in[4];
  const float* b_ih_l0  = (const float*)d_in[5];
  const float* b_hh_l0  = (const float*)d_in[6];
  const float* w_ih_l0r = (const float*)d_in[7];
  const float* w_hh_l0r = (const float*)d_in[8];
  const float* b_ih_l0r = (const float*)d_in[9];
  const float* b_hh_l0r = (const float*)d_in[10];
  const float* w_ih_l1  = (const float*)d_in[11];
  const float* w_hh_l1  = (const float*)d_in[12];
  const float* b_ih_l1  = (const float*)d_in[13];
  const float* b_hh_l1  = (const float*)d_in[14];
  const float* w_ih_l1r = (const float*)d_in[15];
  const float* w_hh_l1r = (const float*)d_in[16];
  const float* b_ih_l1r = (const float*)d_in[17];
  const float* b_hh_l1r = (const float*)d_in[18];
  const float* fc_w     = (const float*)d_in[19];
  const float* fc_b     = (const float*)d_in[20];
  const float* crf_start = (const float*)d_in[21];
  const float* crf_end   = (const float*)d_in[22];
  const float* crf_trans = (const float*)d_in[23];

  float* out = (float*)d_out;          // out[0]=loss, out+1 = logits [ML][9]
  const size_t MiB = 1024 * 1024;
  char* ws = (char*)d_ws;

  // x1 region: 64 MiB f32; x0 (16 MiB) aliased at its start (dead after L0 GEMMs)
  float* x1 = (float*)ws;
  float* x0 = x1;
  char* p = ws + 64 * MiB;

  const bool planA = ws_size >= 322 * MiB;
  const size_t xgBytes = planA ? 128 * MiB : 64 * MiB;
  void* xgf = (void*)p; p += xgBytes;
  void* xgr = (void*)p; p += xgBytes;
  float* hbuf = (float*)p; p += 256 * 1024;          // [2][2][8][2048] f32
  int* bar0 = (int*)p; p += 8192;                    // 16 groups x 64 ints
  int* bar1 = (int*)p; p += 8192;
  float* llh = (float*)p; p += 4096;

  // zero the barrier counters (ws is re-poisoned to 0xAA before every launch)
  hipMemsetAsync(bar0, 0, 2 * 8192, stream);

  if (planA) {
    run_pipeline<float>(emb, X, w_ih_l0, w_hh_l0, b_ih_l0, b_hh_l0,
                        w_ih_l0r, w_hh_l0r, b_ih_l0r, b_hh_l0r,
                        w_ih_l1, w_hh_l1, b_ih_l1, b_hh_l1,
                        w_ih_l1r, w_hh_l1r, b_ih_l1r, b_hh_l1r,
                        x1, x0, (float*)xgf, (float*)xgr, hbuf, bar0, bar1, stream);
  } else {
    run_pipeline<__half>(emb, X, w_ih_l0, w_hh_l0, b_ih_l0, b_hh_l0,
                         w_ih_l0r, w_hh_l0r, b_ih_l0r, b_hh_l0r,
                         w_ih_l1, w_hh_l1, b_ih_l1, b_hh_l1,
                         w_ih_l1r, w_hh_l1r, b_ih_l1r, b_hh_l1r,
                         x1, x0, (__half*)xgf, (__half*)xgr, hbuf, bar0, bar1, stream);
  }

  fc_kernel<<<ML / 4, 256, 0, stream>>>(x1, fc_w, fc_b, out + 1);
  crf_kernel<<<BB, 64, 0, stream>>>(out + 1, labels, crf_start, crf_end, crf_trans, llh);
  finalize_kernel<<<1, 64, 0, stream>>>(llh, out);
}